// Round 2
// baseline (65.095 us; speedup 1.0000x reference)
//
#include <hip/hip_runtime.h>
#include <hip/hip_bf16.h>

typedef float  f32x4  __attribute__((ext_vector_type(4)));
typedef short  s16x8  __attribute__((ext_vector_type(8)));

__device__ __forceinline__ unsigned short f2bf(float f) {
    unsigned int u = __float_as_uint(f);
    unsigned int rnd = 0x7fffu + ((u >> 16) & 1u);   // round-to-nearest-even
    return (unsigned short)((u + rnd) >> 16);
}

// Fully fused: gather directly in MFMA A-frag layout, GEMM, masked-concat store.
// Wave handles 16 output rows. Lane (grp=lane>>4, cl=lane&15) owns
// row (r0+cl), cols {kt*32 + grp*8 + i, i<8} -- exactly the A-fragment.
// B (= Wq^T) staged once per block into frag-linear LDS (lane-linear b128 reads).
__global__ __launch_bounds__(256)
void h2kt_fused(const int* __restrict__ q, const int* __restrict__ a_arr,
                const int* __restrict__ next_q,
                const float* __restrict__ ques_table,
                const float* __restrict__ skill_table,
                const float* __restrict__ diff_table,
                const float* __restrict__ area_table,
                const int* __restrict__ q2s,
                const int* __restrict__ q2d,
                const int* __restrict__ q2a,
                const float* __restrict__ Wq,
                const float* __restrict__ bq,
                float* __restrict__ out,
                int pad_idx)
{
    __shared__ unsigned short Blds[16384];   // 32 frags * 64 lanes * 8 bf16 = 32 KiB

    const int tid = threadIdx.x;

    // ---- stage Wq -> bf16 B-fragments, frag-linear in LDS ----
    // slot s in [0,2048): frag f = s>>6 = jt*4+kt; sub-lane sl = s&63.
    // B[k][col] = Wq[col][k]; lane sl holds Wq[jt*16 + (sl&15)][kt*32 + (sl>>4)*8 + i]
    #pragma unroll
    for (int pass = 0; pass < 8; ++pass) {
        const int s  = pass * 256 + tid;
        const int f  = s >> 6, sl = s & 63;
        const int jt = f >> 2, kt = f & 3;
        const int row = jt * 16 + (sl & 15);
        const int col = kt * 32 + (sl >> 4) * 8;
        const float4* wp = (const float4*)(Wq + row * 128 + col);
        const float4 w0 = wp[0], w1 = wp[1];
        s16x8 v;
        v[0] = (short)f2bf(w0.x); v[1] = (short)f2bf(w0.y);
        v[2] = (short)f2bf(w0.z); v[3] = (short)f2bf(w0.w);
        v[4] = (short)f2bf(w1.x); v[5] = (short)f2bf(w1.y);
        v[6] = (short)f2bf(w1.z); v[7] = (short)f2bf(w1.w);
        *(s16x8*)(Blds + (size_t)s * 8) = v;
    }

    // ---- gather A-fragments straight from tables ----
    const int lane = tid & 63;
    const int wave = tid >> 6;
    const int cl   = lane & 15;
    const int grp  = lane >> 4;
    const int r0   = (blockIdx.x * 4 + wave) * 16;   // 0..65520
    const bool isnq = (r0 >= 32768);
    const int p    = (r0 & 32767) + cl;
    const int qq   = isnq ? next_q[p] : q[p];

    const int4 s03 = *(const int4*)(q2s + (size_t)qq * 8);
    const int4 s47 = *(const int4*)(q2s + (size_t)qq * 8 + 4);
    const int sidx[8] = {s03.x, s03.y, s03.z, s03.w, s47.x, s47.y, s47.z, s47.w};
    int cnt = 0;
    #pragma unroll
    for (int i = 0; i < 8; ++i) cnt += (sidx[i] != pad_idx);
    const float cscale = cnt > 0 ? 1.f / (float)cnt : 0.f;

    const int di = q2d[qq];
    const int ai = q2a[qq];
    const float* qrow = ques_table + (size_t)qq * 128 + grp * 8;
    const float* drow = diff_table + (size_t)di * 128 + grp * 8;
    const float* arow = area_table + (size_t)ai * 128 + grp * 8;

    s16x8 afr[4];
    #pragma unroll
    for (int kt = 0; kt < 4; ++kt) {
        const int off = kt * 32;
        const float4 q0 = *(const float4*)(qrow + off);
        const float4 q1 = *(const float4*)(qrow + off + 4);
        const float4 d0 = *(const float4*)(drow + off);
        const float4 d1 = *(const float4*)(drow + off + 4);
        const float4 a0 = *(const float4*)(arow + off);
        const float4 a1 = *(const float4*)(arow + off + 4);
        float sk[8] = {0.f, 0.f, 0.f, 0.f, 0.f, 0.f, 0.f, 0.f};
        #pragma unroll
        for (int i = 0; i < 8; ++i) {
            if (sidx[i] != pad_idx) {          // pad prob ~0.05% -> near-uniform
                const float* sr = skill_table + (size_t)sidx[i] * 128 + grp * 8 + off;
                const float4 t0 = *(const float4*)(sr);
                const float4 t1 = *(const float4*)(sr + 4);
                sk[0] += t0.x; sk[1] += t0.y; sk[2] += t0.z; sk[3] += t0.w;
                sk[4] += t1.x; sk[5] += t1.y; sk[6] += t1.z; sk[7] += t1.w;
            }
        }
        const float qv[8] = {q0.x, q0.y, q0.z, q0.w, q1.x, q1.y, q1.z, q1.w};
        const float dv[8] = {d0.x, d0.y, d0.z, d0.w, d1.x, d1.y, d1.z, d1.w};
        const float av8[8] = {a0.x, a0.y, a0.z, a0.w, a1.x, a1.y, a1.z, a1.w};
        s16x8 v;
        #pragma unroll
        for (int j = 0; j < 8; ++j) {
            const float rest = sk[j] * cscale + dv[j] + av8[j];
            // q rows: (qe+sk+df+ar)/4 ; nq rows (double-avg quirk): qe/16 + 5/16*rest
            const float e = (!isnq) ? 0.25f * (qv[j] + rest)
                                    : 0.0625f * qv[j] + 0.3125f * rest;
            v[j] = (short)f2bf(e);
        }
        afr[kt] = v;
    }

    __syncthreads();   // Blds ready

    int av[4];
    if (!isnq) {
        #pragma unroll
        for (int r = 0; r < 4; ++r) av[r] = a_arr[r0 + grp * 4 + r];
    }

    // ---- GEMM + fused epilogue ----
    #pragma unroll
    for (int jt = 0; jt < 8; ++jt) {
        f32x4 acc = {0.f, 0.f, 0.f, 0.f};
        #pragma unroll
        for (int kt = 0; kt < 4; ++kt) {
            const s16x8 bf = *(const s16x8*)(Blds + ((size_t)(jt * 4 + kt) * 64 + lane) * 8);
            acc = __builtin_amdgcn_mfma_f32_16x16x32_bf16(afr[kt], bf, acc, 0, 0, 0);
        }
        const float bqv = bq[jt * 16 + cl];
        #pragma unroll
        for (int r = 0; r < 4; ++r) {
            const int g = r0 + grp * 4 + r;
            const float v = acc[r] + bqv;
            if (!isnq) {
                const size_t base = (size_t)g * 384 + jt * 16 + cl;
                const bool on = (av[r] != 0);
                out[base]       = on ? v : 0.f;
                out[base + 128] = on ? 0.f : v;
            } else {
                out[(size_t)(g - 32768) * 384 + 256 + jt * 16 + cl] = v;
            }
        }
    }
}

extern "C" void kernel_launch(void* const* d_in, const int* in_sizes, int n_in,
                              void* d_out, int out_size, void* d_ws, size_t ws_size,
                              hipStream_t stream) {
    const int*   q          = (const int*)d_in[0];
    const int*   a          = (const int*)d_in[1];
    const int*   next_q     = (const int*)d_in[2];
    const float* ques_table = (const float*)d_in[3];
    const float* skill_tab  = (const float*)d_in[4];
    const float* diff_tab   = (const float*)d_in[5];
    const float* area_tab   = (const float*)d_in[6];
    const int*   q2s        = (const int*)d_in[7];
    const int*   q2d        = (const int*)d_in[8];
    const int*   q2a        = (const int*)d_in[9];
    const float* Wq         = (const float*)d_in[10];
    const float* bq         = (const float*)d_in[11];
    float* out = (float*)d_out;

    const int NS = in_sizes[4] / 128;       // 2001
    const int pad_idx = NS - 1;             // 2000

    h2kt_fused<<<1024, 256, 0, stream>>>(q, a, next_q, ques_table, skill_tab,
                                         diff_tab, area_tab, q2s, q2d, q2a,
                                         Wq, bq, out, pad_idx);
}

// Round 3
// 62.278 us; speedup vs baseline: 1.0452x; 1.0452x over previous
//
#include <hip/hip_runtime.h>
#include <hip/hip_bf16.h>

typedef float  f32x4  __attribute__((ext_vector_type(4)));
typedef short  s16x8  __attribute__((ext_vector_type(8)));

__device__ __forceinline__ unsigned short f2bf(float f) {
    unsigned int u = __float_as_uint(f);
    unsigned int rnd = 0x7fffu + ((u >> 16) & 1u);   // round-to-nearest-even
    return (unsigned short)((u + rnd) >> 16);
}

// One-time: Wq (f32 128x128) -> bf16 B-fragments, frag-linear in ws.
// Slot s in [0,2048): frag f=s>>6 = jt*4+kt; sub-lane sl=s&63.
// B[k][col] = Wq[col][k]: lane sl holds Wq[jt*16+(sl&15)][kt*32+(sl>>4)*8 + i], i<8.
__global__ __launch_bounds__(256)
void h2kt_prep(const float* __restrict__ Wq, unsigned short* __restrict__ Wqb) {
    const int s  = blockIdx.x * 256 + threadIdx.x;   // 0..2047
    const int f  = s >> 6, sl = s & 63;
    const int jt = f >> 2, kt = f & 3;
    const int row = jt * 16 + (sl & 15);
    const int col = kt * 32 + (sl >> 4) * 8;
    const float4 w0 = *(const float4*)(Wq + row * 128 + col);
    const float4 w1 = *(const float4*)(Wq + row * 128 + col + 4);
    s16x8 v;
    v[0] = (short)f2bf(w0.x); v[1] = (short)f2bf(w0.y);
    v[2] = (short)f2bf(w0.z); v[3] = (short)f2bf(w0.w);
    v[4] = (short)f2bf(w1.x); v[5] = (short)f2bf(w1.y);
    v[6] = (short)f2bf(w1.z); v[7] = (short)f2bf(w1.w);
    *(s16x8*)(Wqb + (size_t)s * 8) = v;
}

// Fused gather + GEMM + masked-concat store. One wave per 16 output rows.
// No LDS, no barrier; B-frags read lane-linear from L2-hot Wqb.
// __launch_bounds__(64,4): 4 waves/EU floor -> 128-VGPR cap, so the compiler
// can keep ~12 gather float4s in flight (latency hiding was R2's bottleneck).
__global__ __launch_bounds__(64, 4)
void h2kt_fused(const int* __restrict__ q, const int* __restrict__ a_arr,
                const int* __restrict__ next_q,
                const float* __restrict__ ques_table,
                const float* __restrict__ skill_table,
                const float* __restrict__ diff_table,
                const float* __restrict__ area_table,
                const int* __restrict__ q2s,
                const int* __restrict__ q2d,
                const int* __restrict__ q2a,
                const unsigned short* __restrict__ Wqb,
                const float* __restrict__ bq,
                float* __restrict__ out,
                int pad_idx)
{
    const int lane = threadIdx.x;          // 64-thread block = 1 wave
    const int cl   = lane & 15;
    const int grp  = lane >> 4;
    const int r0   = blockIdx.x * 16;      // 0..65520
    const bool isnq = (r0 >= 32768);
    const int p    = (r0 & 32767) + cl;
    const int qq   = isnq ? next_q[p] : q[p];

    // independent loads issued early
    int av[4];
    if (!isnq) {
        #pragma unroll
        for (int r = 0; r < 4; ++r) av[r] = a_arr[r0 + grp * 4 + r];
    }

    const int4 s03 = *(const int4*)(q2s + (size_t)qq * 8);
    const int4 s47 = *(const int4*)(q2s + (size_t)qq * 8 + 4);
    const int di = q2d[qq];
    const int ai = q2a[qq];

    // all 8 ques float4s (the only HBM-latency loads) issued upfront
    const float* qrow = ques_table + (size_t)qq * 128 + grp * 8;
    float4 qv4[8];
    #pragma unroll
    for (int k = 0; k < 4; ++k) {
        qv4[2 * k]     = *(const float4*)(qrow + k * 32);
        qv4[2 * k + 1] = *(const float4*)(qrow + k * 32 + 4);
    }

    const int sidx[8] = {s03.x, s03.y, s03.z, s03.w, s47.x, s47.y, s47.z, s47.w};
    int cnt = 0;
    #pragma unroll
    for (int i = 0; i < 8; ++i) cnt += (sidx[i] != pad_idx);
    const float cscale = cnt > 0 ? 1.f / (float)cnt : 0.f;

    const float* drow = diff_table + (size_t)di * 128 + grp * 8;
    const float* arow = area_table + (size_t)ai * 128 + grp * 8;

    s16x8 afr[4];
    #pragma unroll
    for (int kt = 0; kt < 4; ++kt) {
        const int off = kt * 32;
        f32x4 s0 = {0.f, 0.f, 0.f, 0.f}, s1 = {0.f, 0.f, 0.f, 0.f};
        #pragma unroll
        for (int i = 0; i < 8; ++i) {
            if (sidx[i] != pad_idx) {       // pad prob ~0.05%: near-uniform
                const float* sr = skill_table + (size_t)sidx[i] * 128 + grp * 8 + off;
                s0 += *(const f32x4*)(sr);
                s1 += *(const f32x4*)(sr + 4);
            }
        }
        const f32x4 d0 = *(const f32x4*)(drow + off);
        const f32x4 d1 = *(const f32x4*)(drow + off + 4);
        const f32x4 a0 = *(const f32x4*)(arow + off);
        const f32x4 a1 = *(const f32x4*)(arow + off + 4);
        const f32x4 q0 = *(const f32x4*)&qv4[2 * kt];
        const f32x4 q1 = *(const f32x4*)&qv4[2 * kt + 1];

        const f32x4 rest0 = s0 * cscale + d0 + a0;
        const f32x4 rest1 = s1 * cscale + d1 + a1;
        f32x4 e0, e1;
        if (!isnq) {        // (qe+sk+df+ar)/4
            e0 = 0.25f * (q0 + rest0);
            e1 = 0.25f * (q1 + rest1);
        } else {            // double-avg quirk: qe/16 + 5/16*(sk+df+ar)
            e0 = 0.0625f * q0 + 0.3125f * rest0;
            e1 = 0.0625f * q1 + 0.3125f * rest1;
        }
        s16x8 v;
        #pragma unroll
        for (int j = 0; j < 4; ++j) { v[j] = (short)f2bf(e0[j]); v[j + 4] = (short)f2bf(e1[j]); }
        afr[kt] = v;
    }

    // GEMM + fused epilogue; nontemporal stores keep the 50 MB stream out of L2
    #pragma unroll
    for (int jt = 0; jt < 8; ++jt) {
        f32x4 acc = {0.f, 0.f, 0.f, 0.f};
        #pragma unroll
        for (int kt = 0; kt < 4; ++kt) {
            const s16x8 bf = *(const s16x8*)(Wqb + ((size_t)(jt * 4 + kt) * 64 + lane) * 8);
            acc = __builtin_amdgcn_mfma_f32_16x16x32_bf16(afr[kt], bf, acc, 0, 0, 0);
        }
        const float bqv = bq[jt * 16 + cl];
        #pragma unroll
        for (int r = 0; r < 4; ++r) {
            const int g = r0 + grp * 4 + r;
            const float v = acc[r] + bqv;
            if (!isnq) {
                const size_t base = (size_t)g * 384 + jt * 16 + cl;
                const bool on = (av[r] != 0);
                __builtin_nontemporal_store(on ? v : 0.f, &out[base]);
                __builtin_nontemporal_store(on ? 0.f : v, &out[base + 128]);
            } else {
                __builtin_nontemporal_store(v, &out[(size_t)(g - 32768) * 384 + 256 + jt * 16 + cl]);
            }
        }
    }
}

extern "C" void kernel_launch(void* const* d_in, const int* in_sizes, int n_in,
                              void* d_out, int out_size, void* d_ws, size_t ws_size,
                              hipStream_t stream) {
    const int*   q          = (const int*)d_in[0];
    const int*   a          = (const int*)d_in[1];
    const int*   next_q     = (const int*)d_in[2];
    const float* ques_table = (const float*)d_in[3];
    const float* skill_tab  = (const float*)d_in[4];
    const float* diff_tab   = (const float*)d_in[5];
    const float* area_tab   = (const float*)d_in[6];
    const int*   q2s        = (const int*)d_in[7];
    const int*   q2d        = (const int*)d_in[8];
    const int*   q2a        = (const int*)d_in[9];
    const float* Wq         = (const float*)d_in[10];
    const float* bq         = (const float*)d_in[11];
    float* out = (float*)d_out;

    const int NS = in_sizes[4] / 128;       // 2001
    const int pad_idx = NS - 1;             // 2000

    unsigned short* Wqb = (unsigned short*)d_ws;   // 2048*8 bf16 = 32 KiB

    h2kt_prep<<<8, 256, 0, stream>>>(Wq, Wqb);
    h2kt_fused<<<4096, 64, 0, stream>>>(q, a, next_q, ques_table, skill_tab,
                                        diff_tab, area_tab, q2s, q2d, q2a,
                                        Wqb, bq, out, pad_idx);
}

// Round 4
// 46.093 us; speedup vs baseline: 1.4122x; 1.3511x over previous
//
#include <hip/hip_runtime.h>
#include <hip/hip_bf16.h>

typedef float  f32x4  __attribute__((ext_vector_type(4)));
typedef short  s16x8  __attribute__((ext_vector_type(8)));

__device__ __forceinline__ unsigned short f2bf(float f) {
    unsigned int u = __float_as_uint(f);
    unsigned int rnd = 0x7fffu + ((u >> 16) & 1u);   // round-to-nearest-even
    return (unsigned short)((u + rnd) >> 16);
}

// acc += s * unpack_bf16x8(v)   (v = 8 bf16 packed in 4 u32)
__device__ __forceinline__ void bf8_fma(const s16x8 v, float s, f32x4& a0, f32x4& a1) {
    const uint4 u = *(const uint4*)&v;
    a0[0] += s * __uint_as_float(u.x << 16);
    a0[1] += s * __uint_as_float(u.x & 0xffff0000u);
    a0[2] += s * __uint_as_float(u.y << 16);
    a0[3] += s * __uint_as_float(u.y & 0xffff0000u);
    a1[0] += s * __uint_as_float(u.z << 16);
    a1[1] += s * __uint_as_float(u.z & 0xffff0000u);
    a1[2] += s * __uint_as_float(u.w << 16);
    a1[3] += s * __uint_as_float(u.w & 0xffff0000u);
}

// Prep: skill/diff/area -> bf16 rows (unified table T: skill@0, diff@2001, area@2101)
// and Wq -> bf16 B-fragments frag-linear (slot s: frag f=s>>6=jt*4+kt, sublane sl=s&63,
// holding Wq[jt*16+(sl&15)][kt*32+(sl>>4)*8 + i], i<8).
__global__ __launch_bounds__(256)
void h2kt_prep(const float* __restrict__ Wq, const float* __restrict__ skill,
               const float* __restrict__ diff, const float* __restrict__ area,
               unsigned short* __restrict__ T, unsigned short* __restrict__ Wqb)
{
    const int bid = blockIdx.x, tid = threadIdx.x;
    if (bid < 8) {
        const int s  = bid * 256 + tid;              // 0..2047
        const int f  = s >> 6, sl = s & 63;
        const int jt = f >> 2, kt = f & 3;
        const int row = jt * 16 + (sl & 15);
        const int col = kt * 32 + (sl >> 4) * 8;
        const float4 w0 = *(const float4*)(Wq + row * 128 + col);
        const float4 w1 = *(const float4*)(Wq + row * 128 + col + 4);
        s16x8 v;
        v[0] = (short)f2bf(w0.x); v[1] = (short)f2bf(w0.y);
        v[2] = (short)f2bf(w0.z); v[3] = (short)f2bf(w0.w);
        v[4] = (short)f2bf(w1.x); v[5] = (short)f2bf(w1.y);
        v[6] = (short)f2bf(w1.z); v[7] = (short)f2bf(w1.w);
        *(s16x8*)(Wqb + (size_t)s * 8) = v;
    } else {
        const int row = (bid - 8) * 8 + (tid >> 5);  // 8 rows per block
        if (row < 2151) {
            const int c4 = (tid & 31) * 4;
            const float* src = (row < 2001) ? skill + (size_t)row * 128
                             : (row < 2101) ? diff + (size_t)(row - 2001) * 128
                                            : area + (size_t)(row - 2101) * 128;
            const float4 v = *(const float4*)(src + c4);
            ushort4 o;
            o.x = f2bf(v.x); o.y = f2bf(v.y); o.z = f2bf(v.z); o.w = f2bf(v.w);
            *(ushort4*)(T + (size_t)row * 128 + c4) = o;
        }
    }
}

// Fused main: 2 waves cooperate on one 16-row tile.
//   wave0: qe (f32 HBM) + skill[0..3]  -> weighted partial0 -> LDS P (bf16, padded)
//   wave1: skill[4..7] + diff + area   -> + partial0 -> E -> A-frags -> LDS F
//   both:  GEMM (wave w does jt = w*4..w*4+3) + fused mask/concat epilogue.
__global__ __launch_bounds__(128, 6)
void h2kt_fused(const int* __restrict__ q, const int* __restrict__ a_arr,
                const int* __restrict__ next_q,
                const float* __restrict__ ques_table,
                const int* __restrict__ q2s,
                const int* __restrict__ q2d,
                const int* __restrict__ q2a,
                const unsigned short* __restrict__ T,     // bf16 skill/diff/area
                const unsigned short* __restrict__ Wqb,
                const float* __restrict__ bq,
                float* __restrict__ out,
                int pad_idx)
{
    __shared__ __align__(16) unsigned short P[16 * 136];  // partial0, bf16, padded rows
    __shared__ __align__(16) unsigned short F[4 * 64 * 8];// A-frags, frag-linear

    const int tid  = threadIdx.x;
    const int w    = tid >> 6;
    const int lane = tid & 63;
    const int cl   = lane & 15;
    const int grp  = lane >> 4;
    const int r0   = blockIdx.x * 16;        // 0..65520
    const bool isnq = (r0 >= 32768);
    const int p    = (r0 & 32767) + cl;
    const int qq   = isnq ? next_q[p] : q[p];

    // combine weights: E = wq*qe + wr*(sk_mean + df + ar)
    const float wq_ = isnq ? 0.0625f : 0.25f;
    const float wr_ = isnq ? 0.3125f : 0.25f;

    const int4 s03 = *(const int4*)(q2s + (size_t)qq * 8);
    const int4 s47 = *(const int4*)(q2s + (size_t)qq * 8 + 4);
    const int sidx[8] = {s03.x, s03.y, s03.z, s03.w, s47.x, s47.y, s47.z, s47.w};
    int cnt = 0;
    #pragma unroll
    for (int i = 0; i < 8; ++i) cnt += (sidx[i] != pad_idx);
    const float cs = wr_ * (cnt > 0 ? 1.f / (float)cnt : 0.f);  // folded skill weight

    int av[4];
    if (!isnq) {
        #pragma unroll
        for (int r = 0; r < 4; ++r) av[r] = a_arr[r0 + grp * 4 + r];
    }

    f32x4 e0[4], e1[4];
    #pragma unroll
    for (int kt = 0; kt < 4; ++kt) { e0[kt] = {0,0,0,0}; e1[kt] = {0,0,0,0}; }

    if (w == 0) {
        // ques row (the only HBM-cold gather) + skill[0..3]
        const float* qrow = ques_table + (size_t)qq * 128 + grp * 8;
        #pragma unroll
        for (int kt = 0; kt < 4; ++kt) {
            const f32x4 q0 = *(const f32x4*)(qrow + kt * 32);
            const f32x4 q1 = *(const f32x4*)(qrow + kt * 32 + 4);
            e0[kt] = wq_ * q0; e1[kt] = wq_ * q1;
        }
        #pragma unroll
        for (int i = 0; i < 4; ++i) {
            if (sidx[i] != pad_idx) {
                const unsigned short* sr = T + (size_t)sidx[i] * 128 + grp * 8;
                #pragma unroll
                for (int kt = 0; kt < 4; ++kt)
                    bf8_fma(*(const s16x8*)(sr + kt * 32), cs, e0[kt], e1[kt]);
            }
        }
        // partial0 -> P (bf16), row cl, cols kt*32+grp*8..+7, padded stride 136
        #pragma unroll
        for (int kt = 0; kt < 4; ++kt) {
            s16x8 v;
            #pragma unroll
            for (int j = 0; j < 4; ++j) {
                v[j]     = (short)f2bf(e0[kt][j]);
                v[j + 4] = (short)f2bf(e1[kt][j]);
            }
            *(s16x8*)(P + cl * 136 + kt * 32 + grp * 8) = v;
        }
    } else {
        // skill[4..7] + diff + area (all bf16, L1/L2-hot)
        const int di = q2d[qq];
        const int ai = q2a[qq];
        #pragma unroll
        for (int i = 4; i < 8; ++i) {
            if (sidx[i] != pad_idx) {
                const unsigned short* sr = T + (size_t)sidx[i] * 128 + grp * 8;
                #pragma unroll
                for (int kt = 0; kt < 4; ++kt)
                    bf8_fma(*(const s16x8*)(sr + kt * 32), cs, e0[kt], e1[kt]);
            }
        }
        const unsigned short* dr = T + (size_t)(2001 + di) * 128 + grp * 8;
        const unsigned short* ar = T + (size_t)(2101 + ai) * 128 + grp * 8;
        #pragma unroll
        for (int kt = 0; kt < 4; ++kt) {
            bf8_fma(*(const s16x8*)(dr + kt * 32), wr_, e0[kt], e1[kt]);
            bf8_fma(*(const s16x8*)(ar + kt * 32), wr_, e0[kt], e1[kt]);
        }
    }

    __syncthreads();   // P ready

    s16x8 afr[4];
    if (w == 1) {
        #pragma unroll
        for (int kt = 0; kt < 4; ++kt) {
            const s16x8 pv = *(const s16x8*)(P + cl * 136 + kt * 32 + grp * 8);
            bf8_fma(pv, 1.f, e0[kt], e1[kt]);     // E = partial0 + partial1
            s16x8 v;
            #pragma unroll
            for (int j = 0; j < 4; ++j) {
                v[j]     = (short)f2bf(e0[kt][j]);
                v[j + 4] = (short)f2bf(e1[kt][j]);
            }
            afr[kt] = v;
            *(s16x8*)(F + ((size_t)kt * 64 + lane) * 8) = v;   // lane-linear
        }
    }

    __syncthreads();   // F ready

    if (w == 0) {
        #pragma unroll
        for (int kt = 0; kt < 4; ++kt)
            afr[kt] = *(const s16x8*)(F + ((size_t)kt * 64 + lane) * 8);
    }

    // GEMM: wave w does jt = w*4 .. w*4+3; fused epilogue, nontemporal stores
    #pragma unroll
    for (int jt2 = 0; jt2 < 4; ++jt2) {
        const int jt = w * 4 + jt2;
        f32x4 acc = {0.f, 0.f, 0.f, 0.f};
        #pragma unroll
        for (int kt = 0; kt < 4; ++kt) {
            const s16x8 bf = *(const s16x8*)(Wqb + ((size_t)(jt * 4 + kt) * 64 + lane) * 8);
            acc = __builtin_amdgcn_mfma_f32_16x16x32_bf16(afr[kt], bf, acc, 0, 0, 0);
        }
        const float bqv = bq[jt * 16 + cl];
        #pragma unroll
        for (int r = 0; r < 4; ++r) {
            const int g = r0 + grp * 4 + r;
            const float v = acc[r] + bqv;
            if (!isnq) {
                const size_t base = (size_t)g * 384 + jt * 16 + cl;
                const bool on = (av[r] != 0);
                __builtin_nontemporal_store(on ? v : 0.f, &out[base]);
                __builtin_nontemporal_store(on ? 0.f : v, &out[base + 128]);
            } else {
                __builtin_nontemporal_store(v, &out[(size_t)(g - 32768) * 384 + 256 + jt * 16 + cl]);
            }
        }
    }
}

extern "C" void kernel_launch(void* const* d_in, const int* in_sizes, int n_in,
                              void* d_out, int out_size, void* d_ws, size_t ws_size,
                              hipStream_t stream) {
    const int*   q          = (const int*)d_in[0];
    const int*   a          = (const int*)d_in[1];
    const int*   next_q     = (const int*)d_in[2];
    const float* ques_table = (const float*)d_in[3];
    const float* skill_tab  = (const float*)d_in[4];
    const float* diff_tab   = (const float*)d_in[5];
    const float* area_tab   = (const float*)d_in[6];
    const int*   q2s        = (const int*)d_in[7];
    const int*   q2d        = (const int*)d_in[8];
    const int*   q2a        = (const int*)d_in[9];
    const float* Wq         = (const float*)d_in[10];
    const float* bq         = (const float*)d_in[11];
    float* out = (float*)d_out;

    const int NS = in_sizes[4] / 128;       // 2001
    const int pad_idx = NS - 1;             // 2000

    unsigned short* T   = (unsigned short*)d_ws;            // 2151*128 bf16
    unsigned short* Wqb = T + (size_t)2151 * 128;           // 2048*8 bf16

    h2kt_prep<<<8 + 270, 256, 0, stream>>>(Wq, skill_tab, diff_tab, area_tab, T, Wqb);
    h2kt_fused<<<4096, 128, 0, stream>>>(q, a, next_q, ques_table,
                                         q2s, q2d, q2a, T, Wqb, bq, out, pad_idx);
}

// Round 5
// 44.354 us; speedup vs baseline: 1.4676x; 1.0392x over previous
//
#include <hip/hip_runtime.h>
#include <hip/hip_bf16.h>

typedef float  f32x4  __attribute__((ext_vector_type(4)));
typedef short  s16x8  __attribute__((ext_vector_type(8)));

__device__ __forceinline__ unsigned short f2bf(float f) {
    unsigned int u = __float_as_uint(f);
    unsigned int rnd = 0x7fffu + ((u >> 16) & 1u);   // round-to-nearest-even
    return (unsigned short)((u + rnd) >> 16);
}

// acc += s * unpack_bf16x8(v)
__device__ __forceinline__ void bf8_fma(const s16x8 v, float s, f32x4& a0, f32x4& a1) {
    const uint4 u = *(const uint4*)&v;
    a0[0] += s * __uint_as_float(u.x << 16);
    a0[1] += s * __uint_as_float(u.x & 0xffff0000u);
    a0[2] += s * __uint_as_float(u.y << 16);
    a0[3] += s * __uint_as_float(u.y & 0xffff0000u);
    a1[0] += s * __uint_as_float(u.z << 16);
    a1[1] += s * __uint_as_float(u.z & 0xffff0000u);
    a1[2] += s * __uint_as_float(u.w << 16);
    a1[3] += s * __uint_as_float(u.w & 0xffff0000u);
}

// Wq (f32 128x128) -> bf16 B-fragments, frag-linear.
// slot s: frag f=s>>6=jt*4+kt, sublane sl=s&63 holds Wq[jt*16+(sl&15)][kt*32+(sl>>4)*8+i], i<8.
__global__ __launch_bounds__(256)
void h2kt_prep_wqb(const float* __restrict__ Wq, unsigned short* __restrict__ Wqb) {
    const int s  = blockIdx.x * 256 + threadIdx.x;   // 0..2047
    const int f  = s >> 6, sl = s & 63;
    const int jt = f >> 2, kt = f & 3;
    const int row = jt * 16 + (sl & 15);
    const int col = kt * 32 + (sl >> 4) * 8;
    const float4 w0 = *(const float4*)(Wq + row * 128 + col);
    const float4 w1 = *(const float4*)(Wq + row * 128 + col + 4);
    s16x8 v;
    v[0] = (short)f2bf(w0.x); v[1] = (short)f2bf(w0.y);
    v[2] = (short)f2bf(w0.z); v[3] = (short)f2bf(w0.w);
    v[4] = (short)f2bf(w1.x); v[5] = (short)f2bf(w1.y);
    v[6] = (short)f2bf(w1.z); v[7] = (short)f2bf(w1.w);
    *(s16x8*)(Wqb + (size_t)s * 8) = v;
}

// Pre-transform small tables: T2[r] = table_row @ Wq^T (bf16 row-major).
// Unified rows: skill@0..2000, diff@2001..2100, area@2101..2150.
__global__ __launch_bounds__(64)
void h2kt_prep_tables(const float* __restrict__ skill, const float* __restrict__ diff,
                      const float* __restrict__ area, const unsigned short* __restrict__ Wqb,
                      unsigned short* __restrict__ T2)
{
    const int lane = threadIdx.x;
    const int cl = lane & 15, grp = lane >> 4;
    const int row16 = blockIdx.x * 16;

    int srow = row16 + cl;
    if (srow > 2150) srow = 2150;
    const float* src = (srow < 2001) ? skill + (size_t)srow * 128
                     : (srow < 2101) ? diff + (size_t)(srow - 2001) * 128
                                     : area + (size_t)(srow - 2101) * 128;
    s16x8 afr[4];
    #pragma unroll
    for (int kt = 0; kt < 4; ++kt) {
        const float4 v0 = *(const float4*)(src + kt * 32 + grp * 8);
        const float4 v1 = *(const float4*)(src + kt * 32 + grp * 8 + 4);
        s16x8 v;
        v[0] = (short)f2bf(v0.x); v[1] = (short)f2bf(v0.y);
        v[2] = (short)f2bf(v0.z); v[3] = (short)f2bf(v0.w);
        v[4] = (short)f2bf(v1.x); v[5] = (short)f2bf(v1.y);
        v[6] = (short)f2bf(v1.z); v[7] = (short)f2bf(v1.w);
        afr[kt] = v;
    }
    #pragma unroll
    for (int jt = 0; jt < 8; ++jt) {
        f32x4 acc = {0.f, 0.f, 0.f, 0.f};
        #pragma unroll
        for (int kt = 0; kt < 4; ++kt) {
            const s16x8 bf = *(const s16x8*)(Wqb + ((size_t)(jt * 4 + kt) * 64 + lane) * 8);
            acc = __builtin_amdgcn_mfma_f32_16x16x32_bf16(afr[kt], bf, acc, 0, 0, 0);
        }
        #pragma unroll
        for (int r = 0; r < 4; ++r) {
            const int orow = row16 + grp * 4 + r;
            if (orow < 2151) T2[(size_t)orow * 128 + jt * 16 + cl] = f2bf(acc[r]);
        }
    }
}

// Fused main. 2 waves per 16-row tile; wave w owns rows w*8..w*8+7 for all
// row-major phases and jt-cols w*4..w*4+3 for the MFMA phase.
//   out_row = (wq*qe)@Wq^T + wr*(mean(skill2)+diff2+area2) + bq, masked concat.
__global__ __launch_bounds__(128, 4)
void h2kt_fused(const int* __restrict__ q, const int* __restrict__ a_arr,
                const int* __restrict__ next_q,
                const float* __restrict__ ques_table,
                const int* __restrict__ q2s,
                const int* __restrict__ q2d,
                const int* __restrict__ q2a,
                const unsigned short* __restrict__ T2,
                const unsigned short* __restrict__ Wqb,
                const float* __restrict__ bq,
                float* __restrict__ out,
                int pad_idx)
{
    __shared__ __align__(16) unsigned short Q[16 * 132];   // bf16(wq*qe), pad->264B rows
    __shared__ __align__(16) float         D[16 * 129];    // GEMM result, pad

    const int tid  = threadIdx.x;
    const int w    = tid >> 6;
    const int lane = tid & 63;
    const int cl   = lane & 15;
    const int grp  = lane >> 4;
    const int r0   = blockIdx.x * 16;
    const int base = r0 & 32767;
    const bool isnq = (r0 >= 32768);
    const int* __restrict__ QQ = isnq ? next_q : q;
    const float wq_ = isnq ? 0.0625f : 0.25f;
    const float wr_ = isnq ? 0.3125f : 0.25f;

    // ---- qe gather, ROW-major (2 rows/instr, contiguous), -> bf16(wq*qe) -> LDS Q
    {
        const int r2 = lane >> 5;          // 0/1
        const int c  = lane & 31;          // f32x4 chunk (cols 4c..4c+3)
        int qqv[4];
        #pragma unroll
        for (int p = 0; p < 4; ++p) qqv[p] = QQ[base + w * 8 + p * 2 + r2];
        #pragma unroll
        for (int p = 0; p < 4; ++p) {
            const f32x4 v = *(const f32x4*)(ques_table + (size_t)qqv[p] * 128 + c * 4);
            ushort4 o;
            o.x = f2bf(wq_ * v[0]); o.y = f2bf(wq_ * v[1]);
            o.z = f2bf(wq_ * v[2]); o.w = f2bf(wq_ * v[3]);
            *(ushort4*)(Q + (size_t)(w * 8 + p * 2 + r2) * 132 + c * 4) = o;
        }
    }

    // ---- rest gather, ROW-major (4 rows/pass; lane: row=grp, chunk=cl -> 8 cols)
    // all loads unconditional: pad slot -> weight 0 (row 2000 is a valid finite row)
    f32x4 restA[2], restB[2];
    int avv[2] = {1, 1};
    #pragma unroll
    for (int p = 0; p < 2; ++p) {
        const int row = w * 8 + p * 4 + grp;
        const int pq  = base + row;
        const int qq2 = QQ[pq];
        if (!isnq) avv[p] = a_arr[pq];
        const int4 s03 = *(const int4*)(q2s + (size_t)qq2 * 8);
        const int4 s47 = *(const int4*)(q2s + (size_t)qq2 * 8 + 4);
        const int di = q2d[qq2];
        const int ai = q2a[qq2];
        const int sidx[8] = {s03.x, s03.y, s03.z, s03.w, s47.x, s47.y, s47.z, s47.w};
        int cnt = 0;
        #pragma unroll
        for (int i = 0; i < 8; ++i) cnt += (sidx[i] != pad_idx);
        const float cs = cnt > 0 ? wr_ / (float)cnt : 0.f;

        f32x4 a0 = {0.f, 0.f, 0.f, 0.f}, a1 = {0.f, 0.f, 0.f, 0.f};
        #pragma unroll
        for (int i = 0; i < 8; ++i) {
            const s16x8 sv = *(const s16x8*)(T2 + (size_t)sidx[i] * 128 + cl * 8);
            bf8_fma(sv, (sidx[i] != pad_idx) ? cs : 0.f, a0, a1);
        }
        bf8_fma(*(const s16x8*)(T2 + (size_t)(2001 + di) * 128 + cl * 8), wr_, a0, a1);
        bf8_fma(*(const s16x8*)(T2 + (size_t)(2101 + ai) * 128 + cl * 8), wr_, a0, a1);
        restA[p] = a0; restB[p] = a1;
    }

    __syncthreads();   // Q ready

    // ---- A-frags from LDS + MFMA (wave w does jt = w*4..w*4+3) -> D (LDS)
    s16x8 afr[4];
    #pragma unroll
    for (int kt = 0; kt < 4; ++kt)
        afr[kt] = *(const s16x8*)(Q + (size_t)cl * 132 + kt * 32 + grp * 8);

    #pragma unroll
    for (int jt2 = 0; jt2 < 4; ++jt2) {
        const int jt = w * 4 + jt2;
        f32x4 acc = {0.f, 0.f, 0.f, 0.f};
        #pragma unroll
        for (int kt = 0; kt < 4; ++kt) {
            const s16x8 bf = *(const s16x8*)(Wqb + ((size_t)(jt * 4 + kt) * 64 + lane) * 8);
            acc = __builtin_amdgcn_mfma_f32_16x16x32_bf16(afr[kt], bf, acc, 0, 0, 0);
        }
        #pragma unroll
        for (int r = 0; r < 4; ++r)
            D[(size_t)(grp * 4 + r) * 129 + jt * 16 + cl] = acc[r];
    }

    __syncthreads();   // D ready

    // ---- epilogue: row-major combine + masked concat stores (float4)
    const f32x4 bq0 = *(const f32x4*)(bq + cl * 8);
    const f32x4 bq1 = *(const f32x4*)(bq + cl * 8 + 4);
    const f32x4 z = {0.f, 0.f, 0.f, 0.f};
    #pragma unroll
    for (int p = 0; p < 2; ++p) {
        const int row = w * 8 + p * 4 + grp;
        const f32x4 d0 = *(const f32x4*)(D + (size_t)row * 129 + cl * 8);
        const f32x4 d1 = *(const f32x4*)(D + (size_t)row * 129 + cl * 8 + 4);
        const f32x4 v0 = d0 + restA[p] + bq0;
        const f32x4 v1 = d1 + restB[p] + bq1;
        const size_t orow = (size_t)(base + row);
        if (!isnq) {
            const bool on = (avv[p] != 0);
            *(f32x4*)(out + orow * 384 + cl * 8)           = on ? v0 : z;
            *(f32x4*)(out + orow * 384 + cl * 8 + 4)       = on ? v1 : z;
            *(f32x4*)(out + orow * 384 + 128 + cl * 8)     = on ? z : v0;
            *(f32x4*)(out + orow * 384 + 128 + cl * 8 + 4) = on ? z : v1;
        } else {
            *(f32x4*)(out + orow * 384 + 256 + cl * 8)     = v0;
            *(f32x4*)(out + orow * 384 + 256 + cl * 8 + 4) = v1;
        }
    }
}

extern "C" void kernel_launch(void* const* d_in, const int* in_sizes, int n_in,
                              void* d_out, int out_size, void* d_ws, size_t ws_size,
                              hipStream_t stream) {
    const int*   q          = (const int*)d_in[0];
    const int*   a          = (const int*)d_in[1];
    const int*   next_q     = (const int*)d_in[2];
    const float* ques_table = (const float*)d_in[3];
    const float* skill_tab  = (const float*)d_in[4];
    const float* diff_tab   = (const float*)d_in[5];
    const float* area_tab   = (const float*)d_in[6];
    const int*   q2s        = (const int*)d_in[7];
    const int*   q2d        = (const int*)d_in[8];
    const int*   q2a        = (const int*)d_in[9];
    const float* Wq         = (const float*)d_in[10];
    const float* bq         = (const float*)d_in[11];
    float* out = (float*)d_out;

    const int NS = in_sizes[4] / 128;       // 2001
    const int pad_idx = NS - 1;             // 2000

    unsigned short* Wqb = (unsigned short*)d_ws;            // 2048*8 = 32 KiB
    unsigned short* T2  = Wqb + (size_t)2048 * 8;           // 2151*128 bf16

    h2kt_prep_wqb<<<8, 256, 0, stream>>>(Wq, Wqb);
    h2kt_prep_tables<<<135, 64, 0, stream>>>(skill_tab, diff_tab, area_tab, Wqb, T2);
    h2kt_fused<<<4096, 128, 0, stream>>>(q, a, next_q, ques_table,
                                         q2s, q2d, q2a, T2, Wqb, bq, out, pad_idx);
}